// Round 9
// baseline (55.863 us; speedup 1.0000x reference)
//
#include <hip/hip_runtime.h>

typedef float f4 __attribute__((ext_vector_type(4)));
typedef float f2 __attribute__((ext_vector_type(2)));

#define PAD 68              // LDS row pitch (floats); 68%32=4 spreads banks
#define NBLK 256
#define PART_STRIDE 12288   // 3 * 64*64 floats per block partial

// ws layout (floats):
// [0, 3145728)      partials [256][3][4096]
// [3145728, +256)   bpart[256]
// [3146240, +2)     cnt (grid barrier), cnt2 (final ticket) — memsetAsync'd

__global__ __launch_bounds__(1024) void fused_all_kernel(
    const float* __restrict__ p1, const float* __restrict__ p2,
    float* __restrict__ partials, float* __restrict__ bpart,
    unsigned* __restrict__ cnt, float* __restrict__ out)
{
    __shared__ float la[32 * PAD];
    __shared__ float lb[32 * PAD];
    __shared__ float nred[64][17];
    __shared__ float sa[32], sb[32];
    __shared__ float red2[3][64][17];   // [gram][pc][el] — write-contiguous
    __shared__ float gsum[3][16];
    __shared__ unsigned lastf;
    const int t   = threadIdx.x;
    const int blk = blockIdx.x;
    const int b   = blk >> 5;     // batch 0..7
    const int oi  = blk & 31;     // pooled row strip 0..31

    // ---- phase 1a: pool 4x4 means into LDS [oj][c]   (r3-identical)
    #pragma unroll
    for (int k = 0; k < 2; ++k) {
        const int idx = k * 1024 + t;     // 0..2047
        const int c   = idx >> 5;
        const int oj  = idx & 31;
        const long off = (long)((b * 64 + c) * 128 + oi * 4) * 128 + oj * 4;
        const float* s1 = p1 + off;
        const float* s2 = p2 + off;
        f4 va = *(const f4*)(s1) + *(const f4*)(s1 + 128)
              + *(const f4*)(s1 + 256) + *(const f4*)(s1 + 384);
        f4 vb = *(const f4*)(s2) + *(const f4*)(s2 + 128)
              + *(const f4*)(s2 + 256) + *(const f4*)(s2 + 384);
        la[oj * PAD + c] = ((va[0] + va[1]) + (va[2] + va[3])) * 0.0625f;
        lb[oj * PAD + c] = ((vb[0] + vb[1]) + (vb[2] + vb[3])) * 0.0625f;
    }
    __syncthreads();

    // ---- phase 1b: row L2 norms over 64 channels   (r3-identical)
    {
        const int r = t & 31, g = t >> 5;
        const int m = g >> 4, q = g & 15;
        const float* src = m ? lb : la;
        float ss = 0.f;
        #pragma unroll
        for (int j = 0; j < 4; ++j) {
            const float v = src[r * PAD + q * 4 + j];
            ss = fmaf(v, v, ss);
        }
        nred[m * 32 + r][q] = ss;
    }
    __syncthreads();
    if (t < 64) {
        const int m = t >> 5, r = t & 31;
        float ss = 0.f;
        #pragma unroll
        for (int q = 0; q < 16; ++q) ss += nred[m * 32 + r][q];
        const float rs = 1.0f / fmaxf(sqrtf(ss), 1e-8f);
        if (m) sb[r] = rs; else sa[r] = rs;
    }
    __syncthreads();

    #pragma unroll
    for (int k = 0; k < 2; ++k) {
        const int idx = k * 1024 + t;
        const int c = idx >> 5, oj = idx & 31;
        la[oj * PAD + c] *= sa[oj];
        lb[oj * PAD + c] *= sb[oj];
    }
    __syncthreads();

    // ---- phase 1c: three 64x64 Grams, 2x2 tiles, all 1024 thr (r3-identical)
    const int c1 = (t >> 5) * 2;
    const int c2 = (t & 31) * 2;
    f2 aa0 = {}, aa1 = {}, ab0 = {}, ab1 = {}, bb0 = {}, bb1 = {};

    #pragma unroll 8
    for (int r = 0; r < 32; ++r) {
        const f2 a1 = *(const f2*)&la[r * PAD + c1];
        const f2 a2 = *(const f2*)&la[r * PAD + c2];
        const f2 b1 = *(const f2*)&lb[r * PAD + c1];
        const f2 b2 = *(const f2*)&lb[r * PAD + c2];
        aa0 += a2 * a1[0];  aa1 += a2 * a1[1];
        ab0 += b2 * a1[0];  ab1 += b2 * a1[1];
        bb0 += b2 * b1[0];  bb1 += b2 * b1[1];
    }

    float* P = partials + (long)blk * PART_STRIDE;
    *(f2*)&P[0 * 4096 + (c1    ) * 64 + c2] = aa0;
    *(f2*)&P[0 * 4096 + (c1 + 1) * 64 + c2] = aa1;
    *(f2*)&P[1 * 4096 + (c1    ) * 64 + c2] = ab0;
    *(f2*)&P[1 * 4096 + (c1 + 1) * 64 + c2] = ab1;
    *(f2*)&P[2 * 4096 + (c1    ) * 64 + c2] = bb0;
    *(f2*)&P[2 * 4096 + (c1 + 1) * 64 + c2] = bb1;

    // ---- grid soft barrier: RELEASE arrival (wb L2), RELAXED poll with
    // s_sleep backoff (no cache maintenance per poll!), ONE acquire at exit.
    __syncthreads();
    if (t == 0) {
        __hip_atomic_fetch_add(cnt, 1u, __ATOMIC_RELEASE,
                               __HIP_MEMORY_SCOPE_AGENT);
        while (__hip_atomic_load(cnt, __ATOMIC_RELAXED,
                                 __HIP_MEMORY_SCOPE_AGENT) < NBLK)
            __builtin_amdgcn_s_sleep(4);
        (void)__hip_atomic_load(cnt, __ATOMIC_ACQUIRE,
                                __HIP_MEMORY_SCOPE_AGENT);   // single inv
    }
    __syncthreads();

    // ---- phase 2: block reduces its 16 Gram entries over all 256 partials
    // thread (pc, el): pc = t>>4 (0..63) sums partials 4pc..4pc+3 for entry el.
    {
        const int el = t & 15;
        const int pc = t >> 4;
        const int e  = blk * 16 + el;
        float s0 = 0.f, s1 = 0.f, s2 = 0.f;
        #pragma unroll
        for (int i = 0; i < 4; ++i) {
            const float* Q = partials + (long)(pc * 4 + i) * PART_STRIDE;
            s0 += Q[e];
            s1 += Q[4096 + e];
            s2 += Q[8192 + e];
        }
        red2[0][pc][el] = s0;   // lanes write contiguous (pc*17+el)
        red2[1][pc][el] = s1;
        red2[2][pc][el] = s2;
    }
    __syncthreads();

    if (t < 48) {
        const int g = t >> 4, e2 = t & 15;
        float s = 0.f;
        #pragma unroll
        for (int p = 0; p < 64; ++p) s += red2[g][p][e2];
        gsum[g][e2] = s;
    }
    __syncthreads();

    if (t < 16) {
        const float a = gsum[0][t], m = gsum[1][t], bv = gsum[2][t];
        float v = fmaf(a, a, fmaf(bv, bv, -2.0f * (m * m)));
        v += __shfl_xor(v, 1);
        v += __shfl_xor(v, 2);
        v += __shfl_xor(v, 4);
        v += __shfl_xor(v, 8);
        if (t == 0) {
            __hip_atomic_store(&bpart[blk], v, __ATOMIC_RELEASE,
                               __HIP_MEMORY_SCOPE_AGENT);
            unsigned old = __hip_atomic_fetch_add(cnt + 1, 1u,
                                                  __ATOMIC_ACQ_REL,
                                                  __HIP_MEMORY_SCOPE_AGENT);
            lastf = (old == NBLK - 1) ? 1u : 0u;
        }
    }
    __syncthreads();

    if (lastf) {     // only the last-arriving block enters (block-uniform)
        if (t < 64) {
            const f4 vv = *(const f4*)&bpart[t * 4];
            float v = (vv[0] + vv[1]) + (vv[2] + vv[3]);
            v += __shfl_xor(v, 1);
            v += __shfl_xor(v, 2);
            v += __shfl_xor(v, 4);
            v += __shfl_xor(v, 8);
            v += __shfl_xor(v, 16);
            v += __shfl_xor(v, 32);
            if (t == 0) out[0] = v * (1.0f / 67108864.0f);  // / 8192^2
        }
    }
}

extern "C" void kernel_launch(void* const* d_in, const int* in_sizes, int n_in,
                              void* d_out, int out_size, void* d_ws, size_t ws_size,
                              hipStream_t stream)
{
    const float* p1 = (const float*)d_in[0];
    const float* p2 = (const float*)d_in[1];
    float* ws       = (float*)d_ws;
    float* partials = ws;                           // 256*12288
    float* bpart    = ws + (long)NBLK * PART_STRIDE;
    unsigned* cnt   = (unsigned*)(ws + 3146240);    // cnt, cnt2

    hipMemsetAsync(cnt, 0, 2 * sizeof(unsigned), stream);
    fused_all_kernel<<<NBLK, 1024, 0, stream>>>(p1, p2, partials, bpart, cnt,
                                                (float*)d_out);
}